// Round 21
// baseline (168.264 us; speedup 1.0000x reference)
//
#include <hip/hip_runtime.h>
#include <hip/hip_bf16.h>

// B=4, N=2048, D=1024, H=16, HD=64
#define BATCH 4
#define NSEQ 2048
#define DMODEL 1024
#define NHEAD 16
#define HDIM 64

typedef __attribute__((ext_vector_type(8))) short short8;
typedef __attribute__((ext_vector_type(4))) float f32x4;
typedef __attribute__((ext_vector_type(16))) float f32x16;
typedef __attribute__((ext_vector_type(2))) int int2v;
typedef unsigned short ushort_t;

__device__ __forceinline__ ushort_t f2bf(float f) {
    union { float f; unsigned u; } x; x.f = f;
    unsigned r = x.u + 0x7fffu + ((x.u >> 16) & 1u);   // round-to-nearest-even
    return (ushort_t)(r >> 16);
}

__device__ __forceinline__ unsigned cvt_pk_bf16(float lo, float hi) {
    unsigned r;
    asm("v_cvt_pk_bf16_f32 %0, %1, %2" : "=v"(r) : "v"(lo), "v"(hi));
    return r;
}

// async global->LDS, 16B per lane, dest = wave-uniform base + lane*16
#define GLOAD16(gp, lp) __builtin_amdgcn_global_load_lds(                       \
    (const __attribute__((address_space(1))) unsigned*)(const void*)(gp),       \
    (__attribute__((address_space(3))) unsigned*)(void*)(lp), 16, 0, 0)

// ---------------- fused fp32 -> bf16 convert (single launch, grid-stride) ----
// chunks: 0..12287 = q/k/v (4096 each -> qkv buffer); 12288..14335 = weights.
__global__ __launch_bounds__(256) void cvt_all(const float* __restrict__ q,
                                               const float* __restrict__ k,
                                               const float* __restrict__ v,
                                               const float* __restrict__ w0,
                                               const float* __restrict__ w1,
                                               const float* __restrict__ w2,
                                               const float* __restrict__ w3,
                                               ushort_t* __restrict__ oqkv,
                                               ushort_t* __restrict__ ow) {
    for (int chunk = blockIdx.x; chunk < 14336; chunk += (int)gridDim.x) {
        const float* in;
        ushort_t* out;
        size_t i;
        if (chunk < 12288) {
            int which = chunk >> 12, lb = chunk & 4095;
            in = (which == 0) ? q : ((which == 1) ? k : v);
            i = ((size_t)lb * 256 + threadIdx.x) * 8;
            out = oqkv + (size_t)which * 8388608;
        } else {
            int wb = chunk - 12288;
            int which = wb >> 9, lb = wb & 511;
            in = (which == 0) ? w0 : ((which == 1) ? w1 : ((which == 2) ? w2 : w3));
            i = ((size_t)lb * 256 + threadIdx.x) * 8;
            out = ow + (size_t)which * 1048576;
        }
        float4 f0 = *(const float4*)(in + i);
        float4 f1 = *(const float4*)(in + i + 4);
        short8 o;
        o[0] = f2bf(f0.x); o[1] = f2bf(f0.y); o[2] = f2bf(f0.z); o[3] = f2bf(f0.w);
        o[4] = f2bf(f1.x); o[5] = f2bf(f1.y); o[6] = f2bf(f1.z); o[7] = f2bf(f1.w);
        *(short8*)(out + i) = o;
    }
}

// ---------------- deep-pipelined bf16 GEMM (R7/R11 proven version) -----------
// BM=256 BN=128 BK=64, 512 threads (8 waves, 4Mx2N), 3-slot LDS rotation,
// counted vmcnt(6), T2 XOR-swizzle both sides, T5 setprio.
__device__ __forceinline__ void storeC(float* C, size_t idx, float v) { C[idx] = v; }
__device__ __forceinline__ void storeC(ushort_t* C, size_t idx, float v) { C[idx] = f2bf(v); }

template <typename OutT, int LAYOUT>
__global__ __launch_bounds__(512) void gemm_bt8(const ushort_t* __restrict__ A,
                                                const ushort_t* __restrict__ Bt,
                                                OutT* __restrict__ C,
                                                int M, int N, int K, float alpha) {
    __shared__ ushort_t As[3][256 * 64];
    __shared__ ushort_t Bs[3][128 * 64];

    int tid = threadIdx.x;
    int l = tid & 63, w = tid >> 6;
    int wm = w >> 1, wn = w & 1;
    int lr = l & 15, lk = l >> 4;

    int bid = blockIdx.x;
    int wg = (bid & 7) * 32 + (bid >> 3);
    int nbc = N >> 7;
    int brow = (wg / nbc) << 8;
    int bcol = (wg % nbc) << 7;

    int srow8 = l >> 3;
    int sx = ((l & 7) ^ srow8) * 8;
    const ushort_t* pAsrc = A + (size_t)(brow + w * 32 + srow8) * K + sx;
    const ushort_t* pBsrc = Bt + (size_t)(bcol + w * 16 + srow8) * K + sx;
    const size_t rowK8 = (size_t)8 * K;

    int colx = (lk << 4) ^ ((lr & 7) << 4);
    int abyte = (wm * 64 + lr) * 128 + colx;
    int bbyte = (wn * 64 + lr) * 128 + colx;

    f32x4 acc[4][4] = {};
    const int NT = K >> 6;

#pragma unroll
    for (int c = 0; c < 4; c++) GLOAD16(pAsrc + c * rowK8,      &As[0][(w * 32 + 8 * c) * 64]);
#pragma unroll
    for (int c = 0; c < 2; c++) GLOAD16(pBsrc + c * rowK8,      &Bs[0][(w * 16 + 8 * c) * 64]);
#pragma unroll
    for (int c = 0; c < 4; c++) GLOAD16(pAsrc + c * rowK8 + 64, &As[1][(w * 32 + 8 * c) * 64]);
#pragma unroll
    for (int c = 0; c < 2; c++) GLOAD16(pBsrc + c * rowK8 + 64, &Bs[1][(w * 16 + 8 * c) * 64]);

    int slot = 0, stslot = 2;
    for (int T = 0; T < NT; ++T) {
        if (T < NT - 1) { asm volatile("s_waitcnt vmcnt(6)" ::: "memory"); }
        else            { asm volatile("s_waitcnt vmcnt(0)" ::: "memory"); }
        __builtin_amdgcn_sched_barrier(0);
        __builtin_amdgcn_s_barrier();
        asm volatile("" ::: "memory");

        const char* ab = (const char*)&As[slot][0];
        const char* bb = (const char*)&Bs[slot][0];
        bool stage = (T + 2 < NT);
        int k2 = (T + 2) << 6;

        short8 af[4], bf_[4];
#pragma unroll
        for (int m = 0; m < 4; m++) af[m]  = *(const short8*)(ab + abyte + m * 2048);
#pragma unroll
        for (int n = 0; n < 4; n++) bf_[n] = *(const short8*)(bb + bbyte + n * 2048);
        if (stage) {
            GLOAD16(pAsrc + 0 * rowK8 + k2, &As[stslot][(w * 32 + 0) * 64]);
            GLOAD16(pAsrc + 1 * rowK8 + k2, &As[stslot][(w * 32 + 8) * 64]);
            GLOAD16(pAsrc + 2 * rowK8 + k2, &As[stslot][(w * 32 + 16) * 64]);
        }
        __builtin_amdgcn_s_setprio(1);
#pragma unroll
        for (int m = 0; m < 4; m++)
#pragma unroll
            for (int n = 0; n < 4; n++)
                acc[m][n] = __builtin_amdgcn_mfma_f32_16x16x32_bf16(af[m], bf_[n], acc[m][n], 0, 0, 0);
        __builtin_amdgcn_s_setprio(0);

#pragma unroll
        for (int m = 0; m < 4; m++) af[m]  = *(const short8*)(ab + (abyte ^ 64) + m * 2048);
#pragma unroll
        for (int n = 0; n < 4; n++) bf_[n] = *(const short8*)(bb + (bbyte ^ 64) + n * 2048);
        if (stage) {
            GLOAD16(pAsrc + 3 * rowK8 + k2, &As[stslot][(w * 32 + 24) * 64]);
            GLOAD16(pBsrc + 0 * rowK8 + k2, &Bs[stslot][(w * 16 + 0) * 64]);
            GLOAD16(pBsrc + 1 * rowK8 + k2, &Bs[stslot][(w * 16 + 8) * 64]);
        }
        __builtin_amdgcn_s_setprio(1);
#pragma unroll
        for (int m = 0; m < 4; m++)
#pragma unroll
            for (int n = 0; n < 4; n++)
                acc[m][n] = __builtin_amdgcn_mfma_f32_16x16x32_bf16(af[m], bf_[n], acc[m][n], 0, 0, 0);
        __builtin_amdgcn_s_setprio(0);

        slot = (slot == 2) ? 0 : slot + 1;
        stslot = (stslot == 2) ? 0 : stslot + 1;
    }

#pragma unroll
    for (int m = 0; m < 4; m++)
#pragma unroll
        for (int n = 0; n < 4; n++)
#pragma unroll
            for (int r = 0; r < 4; r++) {
                int row = brow + wm * 64 + m * 16 + lk * 4 + r;
                int col = bcol + wn * 64 + n * 16 + lr;
                float v = acc[m][n][r] * alpha;
                if (LAYOUT == 0) {
                    storeC(C, (size_t)row * N + col, v);
                } else if (LAYOUT == 1) {
                    int b = row >> 11, nn = row & 2047, h = col >> 6, d = col & 63;
                    size_t idx = ((size_t)(b * NHEAD + h) << 17) + ((size_t)(nn >> 5) << 11) +
                                 ((d >> 4) << 9) + ((nn & 31) << 4) + (d & 15);
                    storeC(C, idx, v);
                } else {
                    int b = row >> 11, kk = row & 2047, h = col >> 6, d = col & 63;
                    size_t idx = ((size_t)(b * NHEAD + h) << 17) + ((size_t)(kk >> 6) << 12) +
                                 ((d >> 5) << 11) + (((kk >> 4) & 3) << 9) + ((d & 31) << 4) + (kk & 15);
                    storeC(C, idx, v);
                }
            }
}

// -------- T12 pack: S (f32x16 pair) -> bf16 B-operand fragments --------------
__device__ __forceinline__ void pack_pfr(const f32x16& S0, const f32x16& S1, short8 (&pfr)[4]) {
    unsigned pw0[8], pw1[8];
#pragma unroll
    for (int jj = 0; jj < 8; jj++) {
        pw0[jj] = cvt_pk_bf16(S0[2 * jj], S0[2 * jj + 1]);
        pw1[jj] = cvt_pk_bf16(S1[2 * jj], S1[2 * jj + 1]);
    }
    union U { unsigned u[4]; short8 s; };
    int2v a, bb;
    a  = __builtin_amdgcn_permlane32_swap((int)pw0[0], (int)pw0[2], false, false);
    bb = __builtin_amdgcn_permlane32_swap((int)pw0[1], (int)pw0[3], false, false);
    U u0; u0.u[0] = (unsigned)a[0]; u0.u[1] = (unsigned)bb[0];
          u0.u[2] = (unsigned)a[1]; u0.u[3] = (unsigned)bb[1];
    pfr[0] = u0.s;
    a  = __builtin_amdgcn_permlane32_swap((int)pw0[4], (int)pw0[6], false, false);
    bb = __builtin_amdgcn_permlane32_swap((int)pw0[5], (int)pw0[7], false, false);
    U u1; u1.u[0] = (unsigned)a[0]; u1.u[1] = (unsigned)bb[0];
          u1.u[2] = (unsigned)a[1]; u1.u[3] = (unsigned)bb[1];
    pfr[1] = u1.s;
    a  = __builtin_amdgcn_permlane32_swap((int)pw1[0], (int)pw1[2], false, false);
    bb = __builtin_amdgcn_permlane32_swap((int)pw1[1], (int)pw1[3], false, false);
    U u2; u2.u[0] = (unsigned)a[0]; u2.u[1] = (unsigned)bb[0];
          u2.u[2] = (unsigned)a[1]; u2.u[3] = (unsigned)bb[1];
    pfr[2] = u2.s;
    a  = __builtin_amdgcn_permlane32_swap((int)pw1[4], (int)pw1[6], false, false);
    bb = __builtin_amdgcn_permlane32_swap((int)pw1[5], (int)pw1[7], false, false);
    U u3; u3.u[0] = (unsigned)a[0]; u3.u[1] = (unsigned)bb[0];
          u3.u[2] = (unsigned)a[1]; u3.u[3] = (unsigned)bb[1];
    pfr[3] = u3.s;
}

// ---------------- causal flash attention: paired + XCD-affinity + prefetch ---
// (exact R11 structure: 512 blocks x 256 thr; XCD x = bid&7 hosts heads ≡ x
// (mod 8) -> per-XCD K/V = 4MB = its L2. Wave owns pair (qiL=pi, qiH=63-pi):
// uniform work; K/V fragments loaded ONCE per tile for both blocks; K reg-
// double-buffered. Fixed-shift softmax P = exp2(S-32); no LDS, no barriers.)
__global__ __launch_bounds__(256, 2) void attn_kernel(const ushort_t* __restrict__ Qp,
                                                      const ushort_t* __restrict__ Kp,
                                                      const ushort_t* __restrict__ VT,
                                                      ushort_t* __restrict__ AO) {
    int tid = threadIdx.x;
    int l = tid & 63, w = tid >> 6;
    int lq = l & 31;
    int hi = l >> 5;
    int bid = blockIdx.x;
    int x = bid & 7, jj = bid >> 3;
    int bh = x + 8 * (jj & 7);
    int pi = (jj >> 3) * 4 + w;      // 0..31
    int qiL = pi, qiH = 63 - pi;
    int jlo = (qiL >> 1) + 1;
    int jhi = (qiH >> 1) + 1;
    int b = bh >> 4;

    const size_t hb = (size_t)bh << 17;
    const size_t base = ((size_t)b * NSEQ) * DMODEL + (size_t)(bh & 15) * HDIM;

    int qgL = qiL * 32 + lq;
    int qgH = qiH * 32 + lq;
    int loff = lq * 16 + 8 * hi;

    const ushort_t* kpbase = Kp + hb + loff;
    const ushort_t* vpbase = VT + hb + loff;

    short8 qfL[4], qfH[4];
    {
        const ushort_t* qpL = Qp + hb + ((size_t)qiL << 11) + loff;
        const ushort_t* qpH = Qp + hb + ((size_t)qiH << 11) + loff;
#pragma unroll
        for (int c = 0; c < 4; c++) { qfL[c] = *(const short8*)(qpL + (c << 9));
                                      qfH[c] = *(const short8*)(qpH + (c << 9)); }
    }

    f32x16 OL0 = {}, OL1 = {}, OH0 = {}, OH1 = {};
    float lrunL = 0.f, lrunH = 0.f;

    short8 kA0[4], kA1[4], kB0[4], kB1[4];
#pragma unroll
    for (int c = 0; c < 4; c++) { kA0[c] = *(const short8*)(kpbase + (c << 9));
                                  kA1[c] = *(const short8*)(kpbase + 2048 + (c << 9)); }

    // one tile-step: consume kc*, optionally prefetch next K into kn*
#define ATTN_STEP(kc0, kc1, kn0, kn1, J, PREF) do {                              \
        int j_ = (J); int k0_ = j_ << 6;                                         \
        short8 vf0[4], vf1[4];                                                   \
        { const ushort_t* vp = vpbase + ((size_t)j_ << 12);                      \
          _Pragma("unroll")                                                      \
          for (int c = 0; c < 4; c++) { vf0[c] = *(const short8*)(vp + (c << 9));\
                                        vf1[c] = *(const short8*)(vp + 2048 + (c << 9)); } } \
        /* H: QK -> softmax -> pack */                                           \
        f32x16 S0 = {}, S1 = {};                                                 \
        _Pragma("unroll")                                                        \
        for (int c = 0; c < 4; c++) { S0 = __builtin_amdgcn_mfma_f32_32x32x16_bf16(kc0[c], qfH[c], S0, 0, 0, 0); } \
        _Pragma("unroll")                                                        \
        for (int c = 0; c < 4; c++) { S1 = __builtin_amdgcn_mfma_f32_32x32x16_bf16(kc1[c], qfH[c], S1, 0, 0, 0); } \
        if (j_ == jhi - 1) {                                                     \
            _Pragma("unroll")                                                    \
            for (int r = 0; r < 16; r++) {                                       \
                int kk = k0_ + (r & 3) + 8 * (r >> 2) + 4 * hi;                  \
                if (kk > qgH)      S0[r] = -1e30f;                               \
                if (kk + 32 > qgH) S1[r] = -1e30f;                               \
            }                                                                    \
        }                                                                        \
        float rsH = 0.f;                                                         \
        _Pragma("unroll")                                                        \
        for (int r = 0; r < 16; r++) {                                           \
            S0[r] = __builtin_amdgcn_exp2f(S0[r] - 32.f);                        \
            S1[r] = __builtin_amdgcn_exp2f(S1[r] - 32.f);                        \
            rsH += S0[r] + S1[r];                                                \
        }                                                                        \
        rsH += __shfl_xor(rsH, 32);                                              \
        lrunH += rsH;                                                            \
        short8 pfrH[4];                                                          \
        pack_pfr(S0, S1, pfrH);                                                  \
        /* L: QK (reuses S regs) */                                              \
        bool actL = (j_ < jlo);                                                  \
        if (actL) {                                                              \
            S0 = (f32x16){}; S1 = (f32x16){};                                    \
            _Pragma("unroll")                                                    \
            for (int c = 0; c < 4; c++) { S0 = __builtin_amdgcn_mfma_f32_32x32x16_bf16(kc0[c], qfL[c], S0, 0, 0, 0); } \
            _Pragma("unroll")                                                    \
            for (int c = 0; c < 4; c++) { S1 = __builtin_amdgcn_mfma_f32_32x32x16_bf16(kc1[c], qfL[c], S1, 0, 0, 0); } \
        }                                                                        \
        /* prefetch next K (kc consumed) */                                      \
        if (PREF) {                                                              \
            const ushort_t* kp = kpbase + ((size_t)(2 * (j_ + 1)) << 11);        \
            _Pragma("unroll")                                                    \
            for (int c = 0; c < 4; c++) { kn0[c] = *(const short8*)(kp + (c << 9)); \
                                          kn1[c] = *(const short8*)(kp + 2048 + (c << 9)); } \
        }                                                                        \
        /* PV_H */                                                               \
        _Pragma("unroll")                                                        \
        for (int c = 0; c < 4; c++) { OH0 = __builtin_amdgcn_mfma_f32_32x32x16_bf16(vf0[c], pfrH[c], OH0, 0, 0, 0); } \
        _Pragma("unroll")                                                        \
        for (int c = 0; c < 4; c++) { OH1 = __builtin_amdgcn_mfma_f32_32x32x16_bf16(vf1[c], pfrH[c], OH1, 0, 0, 0); } \
        /* L: softmax -> pack -> PV */                                           \
        if (actL) {                                                              \
            if (j_ == jlo - 1) {                                                 \
                _Pragma("unroll")                                                \
                for (int r = 0; r < 16; r++) {                                   \
                    int kk = k0_ + (r & 3) + 8 * (r >> 2) + 4 * hi;              \
                    if (kk > qgL)      S0[r] = -1e30f;                           \
                    if (kk + 32 > qgL) S1[r] = -1e30f;                           \
                }                                                                \
            }                                                                    \
            float rsL = 0.f;                                                     \
            _Pragma("unroll")                                                    \
            for (int r = 0; r < 16; r++) {                                       \
                S0[r] = __builtin_amdgcn_exp2f(S0[r] - 32.f);                    \
                S1[r] = __builtin_amdgcn_exp2f(S1[r] - 32.f);                    \
                rsL += S0[r] + S1[r];                                            \
            }                                                                    \
            rsL += __shfl_xor(rsL, 32);                                          \
            lrunL += rsL;                                                        \
            short8 pfrL[4];                                                      \
            pack_pfr(S0, S1, pfrL);                                              \
            _Pragma("unroll")                                                    \
            for (int c = 0; c < 4; c++) { OL0 = __builtin_amdgcn_mfma_f32_32x32x16_bf16(vf0[c], pfrL[c], OL0, 0, 0, 0); } \
            _Pragma("unroll")                                                    \
            for (int c = 0; c < 4; c++) { OL1 = __builtin_amdgcn_mfma_f32_32x32x16_bf16(vf1[c], pfrL[c], OL1, 0, 0, 0); } \
        }                                                                        \
    } while (0)

    int j = 0;
    for (; j + 1 < jhi; j += 2) {
        ATTN_STEP(kA0, kA1, kB0, kB1, j, true);
        ATTN_STEP(kB0, kB1, kA0, kA1, j + 1, (j + 2 < jhi));
    }
    if (j < jhi) ATTN_STEP(kA0, kA1, kB0, kB1, j, false);
#undef ATTN_STEP

    // ---- epilogue: both q-blocks ----
    {
        float inv = 1.f / lrunL;
        size_t rowoff = base + (size_t)qgL * DMODEL;
#pragma unroll
        for (int q4 = 0; q4 < 4; q4++) {
            uint2 ua = {cvt_pk_bf16(OL0[4 * q4] * inv,     OL0[4 * q4 + 1] * inv),
                        cvt_pk_bf16(OL0[4 * q4 + 2] * inv, OL0[4 * q4 + 3] * inv)};
            *(uint2*)(AO + rowoff + 8 * q4 + 4 * hi) = ua;
            uint2 ub = {cvt_pk_bf16(OL1[4 * q4] * inv,     OL1[4 * q4 + 1] * inv),
                        cvt_pk_bf16(OL1[4 * q4 + 2] * inv, OL1[4 * q4 + 3] * inv)};
            *(uint2*)(AO + rowoff + 32 + 8 * q4 + 4 * hi) = ub;
        }
    }
    {
        float inv = 1.f / lrunH;
        size_t rowoff = base + (size_t)qgH * DMODEL;
#pragma unroll
        for (int q4 = 0; q4 < 4; q4++) {
            uint2 ua = {cvt_pk_bf16(OH0[4 * q4] * inv,     OH0[4 * q4 + 1] * inv),
                        cvt_pk_bf16(OH0[4 * q4 + 2] * inv, OH0[4 * q4 + 3] * inv)};
            *(uint2*)(AO + rowoff + 8 * q4 + 4 * hi) = ua;
            uint2 ub = {cvt_pk_bf16(OH1[4 * q4] * inv,     OH1[4 * q4 + 1] * inv),
                        cvt_pk_bf16(OH1[4 * q4 + 2] * inv, OH1[4 * q4 + 3] * inv)};
            *(uint2*)(AO + rowoff + 32 + 8 * q4 + 4 * hi) = ub;
        }
    }
}

// ---------------- launch ----------------
extern "C" void kernel_launch(void* const* d_in, const int* in_sizes, int n_in,
                              void* d_out, int out_size, void* d_ws, size_t ws_size,
                              hipStream_t stream) {
    const float* q  = (const float*)d_in[0];
    const float* k  = (const float*)d_in[1];
    const float* v  = (const float*)d_in[2];
    const float* Wq = (const float*)d_in[3];
    const float* Wk = (const float*)d_in[4];
    const float* Wv = (const float*)d_in[5];
    const float* Wo = (const float*)d_in[6];
    float* out = (float*)d_out;

    const size_t BND = (size_t)BATCH * NSEQ * DMODEL;   // 8388608
    const size_t WSZ = (size_t)DMODEL * DMODEL;         // 1048576
    const size_t need = (7 * BND + 4 * WSZ) * sizeof(ushort_t);  // ~120 MB
    if (ws_size < need) return;

    ushort_t* ws  = (ushort_t*)d_ws;
    ushort_t* qb  = ws;
    ushort_t* kb  = qb + BND;
    ushort_t* vb  = kb + BND;
    ushort_t* Qp  = vb + BND;   // fragment-tiled
    ushort_t* Kp  = Qp + BND;   // fragment-tiled
    ushort_t* VT  = Kp + BND;   // fragment-tiled (transposed)
    ushort_t* AO  = VT + BND;   // row-major
    ushort_t* Wqb = AO + BND;   // 4 weights contiguous

    const int M = BATCH * NSEQ;  // 8192

    cvt_all<<<2048, 256, 0, stream>>>(q, k, v, Wq, Wk, Wv, Wo, qb, Wqb);

    int gblocks = (M / 256) * (DMODEL / 128);  // 256 blocks
    // scores scale 1/sqrt(64) * log2(e) folded into Q projection (exp2-domain softmax)
    gemm_bt8<ushort_t, 1><<<gblocks, 512, 0, stream>>>(qb, Wqb, Qp, M, DMODEL, DMODEL, 0.18033688011112043f);
    gemm_bt8<ushort_t, 1><<<gblocks, 512, 0, stream>>>(kb, Wqb + WSZ, Kp, M, DMODEL, DMODEL, 1.0f);
    gemm_bt8<ushort_t, 2><<<gblocks, 512, 0, stream>>>(vb, Wqb + 2 * WSZ, VT, M, DMODEL, DMODEL, 1.0f);

    attn_kernel<<<512, 256, 0, stream>>>(Qp, Kp, VT, AO);

    gemm_bt8<float, 0><<<gblocks, 512, 0, stream>>>(AO, Wqb + 3 * WSZ, out, M, DMODEL, DMODEL, 1.0f);
}

// Round 22
// 168.231 us; speedup vs baseline: 1.0002x; 1.0002x over previous
//
#include <hip/hip_runtime.h>
#include <hip/hip_bf16.h>

// B=4, N=2048, D=1024, H=16, HD=64
#define BATCH 4
#define NSEQ 2048
#define DMODEL 1024
#define NHEAD 16
#define HDIM 64

typedef __attribute__((ext_vector_type(8))) short short8;
typedef __attribute__((ext_vector_type(4))) float f32x4;
typedef __attribute__((ext_vector_type(16))) float f32x16;
typedef __attribute__((ext_vector_type(2))) int int2v;
typedef unsigned short ushort_t;

__device__ __forceinline__ ushort_t f2bf(float f) {
    union { float f; unsigned u; } x; x.f = f;
    unsigned r = x.u + 0x7fffu + ((x.u >> 16) & 1u);   // round-to-nearest-even
    return (ushort_t)(r >> 16);
}

__device__ __forceinline__ unsigned cvt_pk_bf16(float lo, float hi) {
    unsigned r;
    asm("v_cvt_pk_bf16_f32 %0, %1, %2" : "=v"(r) : "v"(lo), "v"(hi));
    return r;
}

// async global->LDS, 16B per lane, dest = wave-uniform base + lane*16
#define GLOAD16(gp, lp) __builtin_amdgcn_global_load_lds(                       \
    (const __attribute__((address_space(1))) unsigned*)(const void*)(gp),       \
    (__attribute__((address_space(3))) unsigned*)(void*)(lp), 16, 0, 0)

// ---------------- fused fp32 -> bf16 convert (single launch, grid-stride) ----
// chunks: 0..12287 = q/k/v (4096 each -> qkv buffer); 12288..14335 = weights.
__global__ __launch_bounds__(256) void cvt_all(const float* __restrict__ q,
                                               const float* __restrict__ k,
                                               const float* __restrict__ v,
                                               const float* __restrict__ w0,
                                               const float* __restrict__ w1,
                                               const float* __restrict__ w2,
                                               const float* __restrict__ w3,
                                               ushort_t* __restrict__ oqkv,
                                               ushort_t* __restrict__ ow) {
    for (int chunk = blockIdx.x; chunk < 14336; chunk += (int)gridDim.x) {
        const float* in;
        ushort_t* out;
        size_t i;
        if (chunk < 12288) {
            int which = chunk >> 12, lb = chunk & 4095;
            in = (which == 0) ? q : ((which == 1) ? k : v);
            i = ((size_t)lb * 256 + threadIdx.x) * 8;
            out = oqkv + (size_t)which * 8388608;
        } else {
            int wb = chunk - 12288;
            int which = wb >> 9, lb = wb & 511;
            in = (which == 0) ? w0 : ((which == 1) ? w1 : ((which == 2) ? w2 : w3));
            i = ((size_t)lb * 256 + threadIdx.x) * 8;
            out = ow + (size_t)which * 1048576;
        }
        float4 f0 = *(const float4*)(in + i);
        float4 f1 = *(const float4*)(in + i + 4);
        short8 o;
        o[0] = f2bf(f0.x); o[1] = f2bf(f0.y); o[2] = f2bf(f0.z); o[3] = f2bf(f0.w);
        o[4] = f2bf(f1.x); o[5] = f2bf(f1.y); o[6] = f2bf(f1.z); o[7] = f2bf(f1.w);
        *(short8*)(out + i) = o;
    }
}

// ---------------- deep-pipelined bf16 GEMM (R7/R11 proven version) -----------
// BM=256 BN=128 BK=64, 512 threads (8 waves, 4Mx2N), 3-slot LDS rotation,
// counted vmcnt(6), T2 XOR-swizzle both sides, T5 setprio.
__device__ __forceinline__ void storeC(float* C, size_t idx, float v) { C[idx] = v; }
__device__ __forceinline__ void storeC(ushort_t* C, size_t idx, float v) { C[idx] = f2bf(v); }

template <typename OutT, int LAYOUT>
__global__ __launch_bounds__(512) void gemm_bt8(const ushort_t* __restrict__ A,
                                                const ushort_t* __restrict__ Bt,
                                                OutT* __restrict__ C,
                                                int M, int N, int K, float alpha) {
    __shared__ ushort_t As[3][256 * 64];
    __shared__ ushort_t Bs[3][128 * 64];

    int tid = threadIdx.x;
    int l = tid & 63, w = tid >> 6;
    int wm = w >> 1, wn = w & 1;
    int lr = l & 15, lk = l >> 4;

    int bid = blockIdx.x;
    int wg = (bid & 7) * 32 + (bid >> 3);
    int nbc = N >> 7;
    int brow = (wg / nbc) << 8;
    int bcol = (wg % nbc) << 7;

    int srow8 = l >> 3;
    int sx = ((l & 7) ^ srow8) * 8;
    const ushort_t* pAsrc = A + (size_t)(brow + w * 32 + srow8) * K + sx;
    const ushort_t* pBsrc = Bt + (size_t)(bcol + w * 16 + srow8) * K + sx;
    const size_t rowK8 = (size_t)8 * K;

    int colx = (lk << 4) ^ ((lr & 7) << 4);
    int abyte = (wm * 64 + lr) * 128 + colx;
    int bbyte = (wn * 64 + lr) * 128 + colx;

    f32x4 acc[4][4] = {};
    const int NT = K >> 6;

#pragma unroll
    for (int c = 0; c < 4; c++) GLOAD16(pAsrc + c * rowK8,      &As[0][(w * 32 + 8 * c) * 64]);
#pragma unroll
    for (int c = 0; c < 2; c++) GLOAD16(pBsrc + c * rowK8,      &Bs[0][(w * 16 + 8 * c) * 64]);
#pragma unroll
    for (int c = 0; c < 4; c++) GLOAD16(pAsrc + c * rowK8 + 64, &As[1][(w * 32 + 8 * c) * 64]);
#pragma unroll
    for (int c = 0; c < 2; c++) GLOAD16(pBsrc + c * rowK8 + 64, &Bs[1][(w * 16 + 8 * c) * 64]);

    int slot = 0, stslot = 2;
    for (int T = 0; T < NT; ++T) {
        if (T < NT - 1) { asm volatile("s_waitcnt vmcnt(6)" ::: "memory"); }
        else            { asm volatile("s_waitcnt vmcnt(0)" ::: "memory"); }
        __builtin_amdgcn_sched_barrier(0);
        __builtin_amdgcn_s_barrier();
        asm volatile("" ::: "memory");

        const char* ab = (const char*)&As[slot][0];
        const char* bb = (const char*)&Bs[slot][0];
        bool stage = (T + 2 < NT);
        int k2 = (T + 2) << 6;

        short8 af[4], bf_[4];
#pragma unroll
        for (int m = 0; m < 4; m++) af[m]  = *(const short8*)(ab + abyte + m * 2048);
#pragma unroll
        for (int n = 0; n < 4; n++) bf_[n] = *(const short8*)(bb + bbyte + n * 2048);
        if (stage) {
            GLOAD16(pAsrc + 0 * rowK8 + k2, &As[stslot][(w * 32 + 0) * 64]);
            GLOAD16(pAsrc + 1 * rowK8 + k2, &As[stslot][(w * 32 + 8) * 64]);
            GLOAD16(pAsrc + 2 * rowK8 + k2, &As[stslot][(w * 32 + 16) * 64]);
        }
        __builtin_amdgcn_s_setprio(1);
#pragma unroll
        for (int m = 0; m < 4; m++)
#pragma unroll
            for (int n = 0; n < 4; n++)
                acc[m][n] = __builtin_amdgcn_mfma_f32_16x16x32_bf16(af[m], bf_[n], acc[m][n], 0, 0, 0);
        __builtin_amdgcn_s_setprio(0);

#pragma unroll
        for (int m = 0; m < 4; m++) af[m]  = *(const short8*)(ab + (abyte ^ 64) + m * 2048);
#pragma unroll
        for (int n = 0; n < 4; n++) bf_[n] = *(const short8*)(bb + (bbyte ^ 64) + n * 2048);
        if (stage) {
            GLOAD16(pAsrc + 3 * rowK8 + k2, &As[stslot][(w * 32 + 24) * 64]);
            GLOAD16(pBsrc + 0 * rowK8 + k2, &Bs[stslot][(w * 16 + 0) * 64]);
            GLOAD16(pBsrc + 1 * rowK8 + k2, &Bs[stslot][(w * 16 + 8) * 64]);
        }
        __builtin_amdgcn_s_setprio(1);
#pragma unroll
        for (int m = 0; m < 4; m++)
#pragma unroll
            for (int n = 0; n < 4; n++)
                acc[m][n] = __builtin_amdgcn_mfma_f32_16x16x32_bf16(af[m], bf_[n], acc[m][n], 0, 0, 0);
        __builtin_amdgcn_s_setprio(0);

        slot = (slot == 2) ? 0 : slot + 1;
        stslot = (stslot == 2) ? 0 : stslot + 1;
    }

#pragma unroll
    for (int m = 0; m < 4; m++)
#pragma unroll
        for (int n = 0; n < 4; n++)
#pragma unroll
            for (int r = 0; r < 4; r++) {
                int row = brow + wm * 64 + m * 16 + lk * 4 + r;
                int col = bcol + wn * 64 + n * 16 + lr;
                float v = acc[m][n][r] * alpha;
                if (LAYOUT == 0) {
                    storeC(C, (size_t)row * N + col, v);
                } else if (LAYOUT == 1) {
                    int b = row >> 11, nn = row & 2047, h = col >> 6, d = col & 63;
                    size_t idx = ((size_t)(b * NHEAD + h) << 17) + ((size_t)(nn >> 5) << 11) +
                                 ((d >> 4) << 9) + ((nn & 31) << 4) + (d & 15);
                    storeC(C, idx, v);
                } else {
                    int b = row >> 11, kk = row & 2047, h = col >> 6, d = col & 63;
                    size_t idx = ((size_t)(b * NHEAD + h) << 17) + ((size_t)(kk >> 6) << 12) +
                                 ((d >> 5) << 11) + (((kk >> 4) & 3) << 9) + ((d & 31) << 4) + (kk & 15);
                    storeC(C, idx, v);
                }
            }
}

// -------- T12 pack: S (f32x16 pair) -> bf16 B-operand fragments --------------
__device__ __forceinline__ void pack_pfr(const f32x16& S0, const f32x16& S1, short8 (&pfr)[4]) {
    unsigned pw0[8], pw1[8];
#pragma unroll
    for (int jj = 0; jj < 8; jj++) {
        pw0[jj] = cvt_pk_bf16(S0[2 * jj], S0[2 * jj + 1]);
        pw1[jj] = cvt_pk_bf16(S1[2 * jj], S1[2 * jj + 1]);
    }
    union U { unsigned u[4]; short8 s; };
    int2v a, bb;
    a  = __builtin_amdgcn_permlane32_swap((int)pw0[0], (int)pw0[2], false, false);
    bb = __builtin_amdgcn_permlane32_swap((int)pw0[1], (int)pw0[3], false, false);
    U u0; u0.u[0] = (unsigned)a[0]; u0.u[1] = (unsigned)bb[0];
          u0.u[2] = (unsigned)a[1]; u0.u[3] = (unsigned)bb[1];
    pfr[0] = u0.s;
    a  = __builtin_amdgcn_permlane32_swap((int)pw0[4], (int)pw0[6], false, false);
    bb = __builtin_amdgcn_permlane32_swap((int)pw0[5], (int)pw0[7], false, false);
    U u1; u1.u[0] = (unsigned)a[0]; u1.u[1] = (unsigned)bb[0];
          u1.u[2] = (unsigned)a[1]; u1.u[3] = (unsigned)bb[1];
    pfr[1] = u1.s;
    a  = __builtin_amdgcn_permlane32_swap((int)pw1[0], (int)pw1[2], false, false);
    bb = __builtin_amdgcn_permlane32_swap((int)pw1[1], (int)pw1[3], false, false);
    U u2; u2.u[0] = (unsigned)a[0]; u2.u[1] = (unsigned)bb[0];
          u2.u[2] = (unsigned)a[1]; u2.u[3] = (unsigned)bb[1];
    pfr[2] = u2.s;
    a  = __builtin_amdgcn_permlane32_swap((int)pw1[4], (int)pw1[6], false, false);
    bb = __builtin_amdgcn_permlane32_swap((int)pw1[5], (int)pw1[7], false, false);
    U u3; u3.u[0] = (unsigned)a[0]; u3.u[1] = (unsigned)bb[0];
          u3.u[2] = (unsigned)a[1]; u3.u[3] = (unsigned)bb[1];
    pfr[3] = u3.s;
}

// ---------------- causal flash attention: paired + XCD-affinity + prefetch ---
// (exact R11 structure: 512 blocks x 256 thr; XCD x = bid&7 hosts heads ≡ x
// (mod 8) -> per-XCD K/V = 4MB = its L2. Wave owns pair (qiL=pi, qiH=63-pi):
// uniform work; K/V fragments loaded ONCE per tile for both blocks; K reg-
// double-buffered. Fixed-shift softmax P = exp2(S-32); no LDS, no barriers.)
__global__ __launch_bounds__(256, 2) void attn_kernel(const ushort_t* __restrict__ Qp,
                                                      const ushort_t* __restrict__ Kp,
                                                      const ushort_t* __restrict__ VT,
                                                      ushort_t* __restrict__ AO) {
    int tid = threadIdx.x;
    int l = tid & 63, w = tid >> 6;
    int lq = l & 31;
    int hi = l >> 5;
    int bid = blockIdx.x;
    int x = bid & 7, jj = bid >> 3;
    int bh = x + 8 * (jj & 7);
    int pi = (jj >> 3) * 4 + w;      // 0..31
    int qiL = pi, qiH = 63 - pi;
    int jlo = (qiL >> 1) + 1;
    int jhi = (qiH >> 1) + 1;
    int b = bh >> 4;

    const size_t hb = (size_t)bh << 17;
    const size_t base = ((size_t)b * NSEQ) * DMODEL + (size_t)(bh & 15) * HDIM;

    int qgL = qiL * 32 + lq;
    int qgH = qiH * 32 + lq;
    int loff = lq * 16 + 8 * hi;

    const ushort_t* kpbase = Kp + hb + loff;
    const ushort_t* vpbase = VT + hb + loff;

    short8 qfL[4], qfH[4];
    {
        const ushort_t* qpL = Qp + hb + ((size_t)qiL << 11) + loff;
        const ushort_t* qpH = Qp + hb + ((size_t)qiH << 11) + loff;
#pragma unroll
        for (int c = 0; c < 4; c++) { qfL[c] = *(const short8*)(qpL + (c << 9));
                                      qfH[c] = *(const short8*)(qpH + (c << 9)); }
    }

    f32x16 OL0 = {}, OL1 = {}, OH0 = {}, OH1 = {};
    float lrunL = 0.f, lrunH = 0.f;

    short8 kA0[4], kA1[4], kB0[4], kB1[4];
#pragma unroll
    for (int c = 0; c < 4; c++) { kA0[c] = *(const short8*)(kpbase + (c << 9));
                                  kA1[c] = *(const short8*)(kpbase + 2048 + (c << 9)); }

    // one tile-step: consume kc*, optionally prefetch next K into kn*
#define ATTN_STEP(kc0, kc1, kn0, kn1, J, PREF) do {                              \
        int j_ = (J); int k0_ = j_ << 6;                                         \
        short8 vf0[4], vf1[4];                                                   \
        { const ushort_t* vp = vpbase + ((size_t)j_ << 12);                      \
          _Pragma("unroll")                                                      \
          for (int c = 0; c < 4; c++) { vf0[c] = *(const short8*)(vp + (c << 9));\
                                        vf1[c] = *(const short8*)(vp + 2048 + (c << 9)); } } \
        /* H: QK -> softmax -> pack */                                           \
        f32x16 S0 = {}, S1 = {};                                                 \
        _Pragma("unroll")                                                        \
        for (int c = 0; c < 4; c++) { S0 = __builtin_amdgcn_mfma_f32_32x32x16_bf16(kc0[c], qfH[c], S0, 0, 0, 0); } \
        _Pragma("unroll")                                                        \
        for (int c = 0; c < 4; c++) { S1 = __builtin_amdgcn_mfma_f32_32x32x16_bf16(kc1[c], qfH[c], S1, 0, 0, 0); } \
        if (j_ == jhi - 1) {                                                     \
            _Pragma("unroll")                                                    \
            for (int r = 0; r < 16; r++) {                                       \
                int kk = k0_ + (r & 3) + 8 * (r >> 2) + 4 * hi;                  \
                if (kk > qgH)      S0[r] = -1e30f;                               \
                if (kk + 32 > qgH) S1[r] = -1e30f;                               \
            }                                                                    \
        }                                                                        \
        float rsH = 0.f;                                                         \
        _Pragma("unroll")                                                        \
        for (int r = 0; r < 16; r++) {                                           \
            S0[r] = __builtin_amdgcn_exp2f(S0[r] - 32.f);                        \
            S1[r] = __builtin_amdgcn_exp2f(S1[r] - 32.f);                        \
            rsH += S0[r] + S1[r];                                                \
        }                                                                        \
        rsH += __shfl_xor(rsH, 32);                                              \
        lrunH += rsH;                                                            \
        short8 pfrH[4];                                                          \
        pack_pfr(S0, S1, pfrH);                                                  \
        /* L: QK (reuses S regs) */                                              \
        bool actL = (j_ < jlo);                                                  \
        if (actL) {                                                              \
            S0 = (f32x16){}; S1 = (f32x16){};                                    \
            _Pragma("unroll")                                                    \
            for (int c = 0; c < 4; c++) { S0 = __builtin_amdgcn_mfma_f32_32x32x16_bf16(kc0[c], qfL[c], S0, 0, 0, 0); } \
            _Pragma("unroll")                                                    \
            for (int c = 0; c < 4; c++) { S1 = __builtin_amdgcn_mfma_f32_32x32x16_bf16(kc1[c], qfL[c], S1, 0, 0, 0); } \
        }                                                                        \
        /* prefetch next K (kc consumed) */                                      \
        if (PREF) {                                                              \
            const ushort_t* kp = kpbase + ((size_t)(2 * (j_ + 1)) << 11);        \
            _Pragma("unroll")                                                    \
            for (int c = 0; c < 4; c++) { kn0[c] = *(const short8*)(kp + (c << 9)); \
                                          kn1[c] = *(const short8*)(kp + 2048 + (c << 9)); } \
        }                                                                        \
        /* PV_H */                                                               \
        _Pragma("unroll")                                                        \
        for (int c = 0; c < 4; c++) { OH0 = __builtin_amdgcn_mfma_f32_32x32x16_bf16(vf0[c], pfrH[c], OH0, 0, 0, 0); } \
        _Pragma("unroll")                                                        \
        for (int c = 0; c < 4; c++) { OH1 = __builtin_amdgcn_mfma_f32_32x32x16_bf16(vf1[c], pfrH[c], OH1, 0, 0, 0); } \
        /* L: softmax -> pack -> PV */                                           \
        if (actL) {                                                              \
            if (j_ == jlo - 1) {                                                 \
                _Pragma("unroll")                                                \
                for (int r = 0; r < 16; r++) {                                   \
                    int kk = k0_ + (r & 3) + 8 * (r >> 2) + 4 * hi;              \
                    if (kk > qgL)      S0[r] = -1e30f;                           \
                    if (kk + 32 > qgL) S1[r] = -1e30f;                           \
                }                                                                \
            }                                                                    \
            float rsL = 0.f;                                                     \
            _Pragma("unroll")                                                    \
            for (int r = 0; r < 16; r++) {                                       \
                S0[r] = __builtin_amdgcn_exp2f(S0[r] - 32.f);                    \
                S1[r] = __builtin_amdgcn_exp2f(S1[r] - 32.f);                    \
                rsL += S0[r] + S1[r];                                            \
            }                                                                    \
            rsL += __shfl_xor(rsL, 32);                                          \
            lrunL += rsL;                                                        \
            short8 pfrL[4];                                                      \
            pack_pfr(S0, S1, pfrL);                                              \
            _Pragma("unroll")                                                    \
            for (int c = 0; c < 4; c++) { OL0 = __builtin_amdgcn_mfma_f32_32x32x16_bf16(vf0[c], pfrL[c], OL0, 0, 0, 0); } \
            _Pragma("unroll")                                                    \
            for (int c = 0; c < 4; c++) { OL1 = __builtin_amdgcn_mfma_f32_32x32x16_bf16(vf1[c], pfrL[c], OL1, 0, 0, 0); } \
        }                                                                        \
    } while (0)

    int j = 0;
    for (; j + 1 < jhi; j += 2) {
        ATTN_STEP(kA0, kA1, kB0, kB1, j, true);
        ATTN_STEP(kB0, kB1, kA0, kA1, j + 1, (j + 2 < jhi));
    }
    if (j < jhi) ATTN_STEP(kA0, kA1, kB0, kB1, j, false);
#undef ATTN_STEP

    // ---- epilogue: both q-blocks ----
    {
        float inv = 1.f / lrunL;
        size_t rowoff = base + (size_t)qgL * DMODEL;
#pragma unroll
        for (int q4 = 0; q4 < 4; q4++) {
            uint2 ua = {cvt_pk_bf16(OL0[4 * q4] * inv,     OL0[4 * q4 + 1] * inv),
                        cvt_pk_bf16(OL0[4 * q4 + 2] * inv, OL0[4 * q4 + 3] * inv)};
            *(uint2*)(AO + rowoff + 8 * q4 + 4 * hi) = ua;
            uint2 ub = {cvt_pk_bf16(OL1[4 * q4] * inv,     OL1[4 * q4 + 1] * inv),
                        cvt_pk_bf16(OL1[4 * q4 + 2] * inv, OL1[4 * q4 + 3] * inv)};
            *(uint2*)(AO + rowoff + 32 + 8 * q4 + 4 * hi) = ub;
        }
    }
    {
        float inv = 1.f / lrunH;
        size_t rowoff = base + (size_t)qgH * DMODEL;
#pragma unroll
        for (int q4 = 0; q4 < 4; q4++) {
            uint2 ua = {cvt_pk_bf16(OH0[4 * q4] * inv,     OH0[4 * q4 + 1] * inv),
                        cvt_pk_bf16(OH0[4 * q4 + 2] * inv, OH0[4 * q4 + 3] * inv)};
            *(uint2*)(AO + rowoff + 8 * q4 + 4 * hi) = ua;
            uint2 ub = {cvt_pk_bf16(OH1[4 * q4] * inv,     OH1[4 * q4 + 1] * inv),
                        cvt_pk_bf16(OH1[4 * q4 + 2] * inv, OH1[4 * q4 + 3] * inv)};
            *(uint2*)(AO + rowoff + 32 + 8 * q4 + 4 * hi) = ub;
        }
    }
}

// ---------------- launch ----------------
extern "C" void kernel_launch(void* const* d_in, const int* in_sizes, int n_in,
                              void* d_out, int out_size, void* d_ws, size_t ws_size,
                              hipStream_t stream) {
    const float* q  = (const float*)d_in[0];
    const float* k  = (const float*)d_in[1];
    const float* v  = (const float*)d_in[2];
    const float* Wq = (const float*)d_in[3];
    const float* Wk = (const float*)d_in[4];
    const float* Wv = (const float*)d_in[5];
    const float* Wo = (const float*)d_in[6];
    float* out = (float*)d_out;

    const size_t BND = (size_t)BATCH * NSEQ * DMODEL;   // 8388608
    const size_t WSZ = (size_t)DMODEL * DMODEL;         // 1048576
    const size_t need = (7 * BND + 4 * WSZ) * sizeof(ushort_t);  // ~120 MB
    if (ws_size < need) return;

    ushort_t* ws  = (ushort_t*)d_ws;
    ushort_t* qb  = ws;
    ushort_t* kb  = qb + BND;
    ushort_t* vb  = kb + BND;
    ushort_t* Qp  = vb + BND;   // fragment-tiled
    ushort_t* Kp  = Qp + BND;   // fragment-tiled
    ushort_t* VT  = Kp + BND;   // fragment-tiled (transposed)
    ushort_t* AO  = VT + BND;   // row-major
    ushort_t* Wqb = AO + BND;   // 4 weights contiguous

    const int M = BATCH * NSEQ;  // 8192

    cvt_all<<<2048, 256, 0, stream>>>(q, k, v, Wq, Wk, Wv, Wo, qb, Wqb);

    int gblocks = (M / 256) * (DMODEL / 128);  // 256 blocks
    // scores scale 1/sqrt(64) * log2(e) folded into Q projection (exp2-domain softmax)
    gemm_bt8<ushort_t, 1><<<gblocks, 512, 0, stream>>>(qb, Wqb, Qp, M, DMODEL, DMODEL, 0.18033688011112043f);
    gemm_bt8<ushort_t, 1><<<gblocks, 512, 0, stream>>>(kb, Wqb + WSZ, Kp, M, DMODEL, DMODEL, 1.0f);
    gemm_bt8<ushort_t, 2><<<gblocks, 512, 0, stream>>>(vb, Wqb + 2 * WSZ, VT, M, DMODEL, DMODEL, 1.0f);

    attn_kernel<<<512, 256, 0, stream>>>(Qp, Kp, VT, AO);

    gemm_bt8<float, 0><<<gblocks, 512, 0, stream>>>(AO, Wqb + 3 * WSZ, out, M, DMODEL, DMODEL, 1.0f);
}

// Round 23
// 167.855 us; speedup vs baseline: 1.0024x; 1.0022x over previous
//
#include <hip/hip_runtime.h>
#include <hip/hip_bf16.h>

// B=4, N=2048, D=1024, H=16, HD=64
#define BATCH 4
#define NSEQ 2048
#define DMODEL 1024
#define NHEAD 16
#define HDIM 64

typedef __attribute__((ext_vector_type(8))) short short8;
typedef __attribute__((ext_vector_type(4))) float f32x4;
typedef __attribute__((ext_vector_type(16))) float f32x16;
typedef __attribute__((ext_vector_type(2))) int int2v;
typedef unsigned short ushort_t;

__device__ __forceinline__ ushort_t f2bf(float f) {
    union { float f; unsigned u; } x; x.f = f;
    unsigned r = x.u + 0x7fffu + ((x.u >> 16) & 1u);   // round-to-nearest-even
    return (ushort_t)(r >> 16);
}

__device__ __forceinline__ unsigned cvt_pk_bf16(float lo, float hi) {
    unsigned r;
    asm("v_cvt_pk_bf16_f32 %0, %1, %2" : "=v"(r) : "v"(lo), "v"(hi));
    return r;
}

// async global->LDS, 16B per lane, dest = wave-uniform base + lane*16
#define GLOAD16(gp, lp) __builtin_amdgcn_global_load_lds(                       \
    (const __attribute__((address_space(1))) unsigned*)(const void*)(gp),       \
    (__attribute__((address_space(3))) unsigned*)(void*)(lp), 16, 0, 0)

// ---------------- fused fp32 -> bf16 convert (single launch, grid-stride) ----
// chunks: 0..12287 = q/k/v (4096 each -> qkv buffer); 12288..14335 = weights.
__global__ __launch_bounds__(256) void cvt_all(const float* __restrict__ q,
                                               const float* __restrict__ k,
                                               const float* __restrict__ v,
                                               const float* __restrict__ w0,
                                               const float* __restrict__ w1,
                                               const float* __restrict__ w2,
                                               const float* __restrict__ w3,
                                               ushort_t* __restrict__ oqkv,
                                               ushort_t* __restrict__ ow) {
    for (int chunk = blockIdx.x; chunk < 14336; chunk += (int)gridDim.x) {
        const float* in;
        ushort_t* out;
        size_t i;
        if (chunk < 12288) {
            int which = chunk >> 12, lb = chunk & 4095;
            in = (which == 0) ? q : ((which == 1) ? k : v);
            i = ((size_t)lb * 256 + threadIdx.x) * 8;
            out = oqkv + (size_t)which * 8388608;
        } else {
            int wb = chunk - 12288;
            int which = wb >> 9, lb = wb & 511;
            in = (which == 0) ? w0 : ((which == 1) ? w1 : ((which == 2) ? w2 : w3));
            i = ((size_t)lb * 256 + threadIdx.x) * 8;
            out = ow + (size_t)which * 1048576;
        }
        float4 f0 = *(const float4*)(in + i);
        float4 f1 = *(const float4*)(in + i + 4);
        short8 o;
        o[0] = f2bf(f0.x); o[1] = f2bf(f0.y); o[2] = f2bf(f0.z); o[3] = f2bf(f0.w);
        o[4] = f2bf(f1.x); o[5] = f2bf(f1.y); o[6] = f2bf(f1.z); o[7] = f2bf(f1.w);
        *(short8*)(out + i) = o;
    }
}

// ---------------- deep-pipelined bf16 GEMM (R7/R11 proven version) -----------
// BM=256 BN=128 BK=64, 512 threads (8 waves, 4Mx2N), 3-slot LDS rotation,
// counted vmcnt(6), T2 XOR-swizzle both sides, T5 setprio.
__device__ __forceinline__ void storeC(float* C, size_t idx, float v) { C[idx] = v; }
__device__ __forceinline__ void storeC(ushort_t* C, size_t idx, float v) { C[idx] = f2bf(v); }

template <typename OutT, int LAYOUT>
__global__ __launch_bounds__(512) void gemm_bt8(const ushort_t* __restrict__ A,
                                                const ushort_t* __restrict__ Bt,
                                                OutT* __restrict__ C,
                                                int M, int N, int K, float alpha) {
    __shared__ ushort_t As[3][256 * 64];
    __shared__ ushort_t Bs[3][128 * 64];

    int tid = threadIdx.x;
    int l = tid & 63, w = tid >> 6;
    int wm = w >> 1, wn = w & 1;
    int lr = l & 15, lk = l >> 4;

    int bid = blockIdx.x;
    int wg = (bid & 7) * 32 + (bid >> 3);
    int nbc = N >> 7;
    int brow = (wg / nbc) << 8;
    int bcol = (wg % nbc) << 7;

    int srow8 = l >> 3;
    int sx = ((l & 7) ^ srow8) * 8;
    const ushort_t* pAsrc = A + (size_t)(brow + w * 32 + srow8) * K + sx;
    const ushort_t* pBsrc = Bt + (size_t)(bcol + w * 16 + srow8) * K + sx;
    const size_t rowK8 = (size_t)8 * K;

    int colx = (lk << 4) ^ ((lr & 7) << 4);
    int abyte = (wm * 64 + lr) * 128 + colx;
    int bbyte = (wn * 64 + lr) * 128 + colx;

    f32x4 acc[4][4] = {};
    const int NT = K >> 6;

#pragma unroll
    for (int c = 0; c < 4; c++) GLOAD16(pAsrc + c * rowK8,      &As[0][(w * 32 + 8 * c) * 64]);
#pragma unroll
    for (int c = 0; c < 2; c++) GLOAD16(pBsrc + c * rowK8,      &Bs[0][(w * 16 + 8 * c) * 64]);
#pragma unroll
    for (int c = 0; c < 4; c++) GLOAD16(pAsrc + c * rowK8 + 64, &As[1][(w * 32 + 8 * c) * 64]);
#pragma unroll
    for (int c = 0; c < 2; c++) GLOAD16(pBsrc + c * rowK8 + 64, &Bs[1][(w * 16 + 8 * c) * 64]);

    int slot = 0, stslot = 2;
    for (int T = 0; T < NT; ++T) {
        if (T < NT - 1) { asm volatile("s_waitcnt vmcnt(6)" ::: "memory"); }
        else            { asm volatile("s_waitcnt vmcnt(0)" ::: "memory"); }
        __builtin_amdgcn_sched_barrier(0);
        __builtin_amdgcn_s_barrier();
        asm volatile("" ::: "memory");

        const char* ab = (const char*)&As[slot][0];
        const char* bb = (const char*)&Bs[slot][0];
        bool stage = (T + 2 < NT);
        int k2 = (T + 2) << 6;

        short8 af[4], bf_[4];
#pragma unroll
        for (int m = 0; m < 4; m++) af[m]  = *(const short8*)(ab + abyte + m * 2048);
#pragma unroll
        for (int n = 0; n < 4; n++) bf_[n] = *(const short8*)(bb + bbyte + n * 2048);
        if (stage) {
            GLOAD16(pAsrc + 0 * rowK8 + k2, &As[stslot][(w * 32 + 0) * 64]);
            GLOAD16(pAsrc + 1 * rowK8 + k2, &As[stslot][(w * 32 + 8) * 64]);
            GLOAD16(pAsrc + 2 * rowK8 + k2, &As[stslot][(w * 32 + 16) * 64]);
        }
        __builtin_amdgcn_s_setprio(1);
#pragma unroll
        for (int m = 0; m < 4; m++)
#pragma unroll
            for (int n = 0; n < 4; n++)
                acc[m][n] = __builtin_amdgcn_mfma_f32_16x16x32_bf16(af[m], bf_[n], acc[m][n], 0, 0, 0);
        __builtin_amdgcn_s_setprio(0);

#pragma unroll
        for (int m = 0; m < 4; m++) af[m]  = *(const short8*)(ab + (abyte ^ 64) + m * 2048);
#pragma unroll
        for (int n = 0; n < 4; n++) bf_[n] = *(const short8*)(bb + (bbyte ^ 64) + n * 2048);
        if (stage) {
            GLOAD16(pAsrc + 3 * rowK8 + k2, &As[stslot][(w * 32 + 24) * 64]);
            GLOAD16(pBsrc + 0 * rowK8 + k2, &Bs[stslot][(w * 16 + 0) * 64]);
            GLOAD16(pBsrc + 1 * rowK8 + k2, &Bs[stslot][(w * 16 + 8) * 64]);
        }
        __builtin_amdgcn_s_setprio(1);
#pragma unroll
        for (int m = 0; m < 4; m++)
#pragma unroll
            for (int n = 0; n < 4; n++)
                acc[m][n] = __builtin_amdgcn_mfma_f32_16x16x32_bf16(af[m], bf_[n], acc[m][n], 0, 0, 0);
        __builtin_amdgcn_s_setprio(0);

        slot = (slot == 2) ? 0 : slot + 1;
        stslot = (stslot == 2) ? 0 : stslot + 1;
    }

#pragma unroll
    for (int m = 0; m < 4; m++)
#pragma unroll
        for (int n = 0; n < 4; n++)
#pragma unroll
            for (int r = 0; r < 4; r++) {
                int row = brow + wm * 64 + m * 16 + lk * 4 + r;
                int col = bcol + wn * 64 + n * 16 + lr;
                float v = acc[m][n][r] * alpha;
                if (LAYOUT == 0) {
                    storeC(C, (size_t)row * N + col, v);
                } else if (LAYOUT == 1) {
                    int b = row >> 11, nn = row & 2047, h = col >> 6, d = col & 63;
                    size_t idx = ((size_t)(b * NHEAD + h) << 17) + ((size_t)(nn >> 5) << 11) +
                                 ((d >> 4) << 9) + ((nn & 31) << 4) + (d & 15);
                    storeC(C, idx, v);
                } else {
                    int b = row >> 11, kk = row & 2047, h = col >> 6, d = col & 63;
                    size_t idx = ((size_t)(b * NHEAD + h) << 17) + ((size_t)(kk >> 6) << 12) +
                                 ((d >> 5) << 11) + (((kk >> 4) & 3) << 9) + ((d & 31) << 4) + (kk & 15);
                    storeC(C, idx, v);
                }
            }
}

// -------- T12 pack: S (f32x16 pair) -> bf16 B-operand fragments --------------
__device__ __forceinline__ void pack_pfr(const f32x16& S0, const f32x16& S1, short8 (&pfr)[4]) {
    unsigned pw0[8], pw1[8];
#pragma unroll
    for (int jj = 0; jj < 8; jj++) {
        pw0[jj] = cvt_pk_bf16(S0[2 * jj], S0[2 * jj + 1]);
        pw1[jj] = cvt_pk_bf16(S1[2 * jj], S1[2 * jj + 1]);
    }
    union U { unsigned u[4]; short8 s; };
    int2v a, bb;
    a  = __builtin_amdgcn_permlane32_swap((int)pw0[0], (int)pw0[2], false, false);
    bb = __builtin_amdgcn_permlane32_swap((int)pw0[1], (int)pw0[3], false, false);
    U u0; u0.u[0] = (unsigned)a[0]; u0.u[1] = (unsigned)bb[0];
          u0.u[2] = (unsigned)a[1]; u0.u[3] = (unsigned)bb[1];
    pfr[0] = u0.s;
    a  = __builtin_amdgcn_permlane32_swap((int)pw0[4], (int)pw0[6], false, false);
    bb = __builtin_amdgcn_permlane32_swap((int)pw0[5], (int)pw0[7], false, false);
    U u1; u1.u[0] = (unsigned)a[0]; u1.u[1] = (unsigned)bb[0];
          u1.u[2] = (unsigned)a[1]; u1.u[3] = (unsigned)bb[1];
    pfr[1] = u1.s;
    a  = __builtin_amdgcn_permlane32_swap((int)pw1[0], (int)pw1[2], false, false);
    bb = __builtin_amdgcn_permlane32_swap((int)pw1[1], (int)pw1[3], false, false);
    U u2; u2.u[0] = (unsigned)a[0]; u2.u[1] = (unsigned)bb[0];
          u2.u[2] = (unsigned)a[1]; u2.u[3] = (unsigned)bb[1];
    pfr[2] = u2.s;
    a  = __builtin_amdgcn_permlane32_swap((int)pw1[4], (int)pw1[6], false, false);
    bb = __builtin_amdgcn_permlane32_swap((int)pw1[5], (int)pw1[7], false, false);
    U u3; u3.u[0] = (unsigned)a[0]; u3.u[1] = (unsigned)bb[0];
          u3.u[2] = (unsigned)a[1]; u3.u[3] = (unsigned)bb[1];
    pfr[3] = u3.s;
}

// ---------------- causal flash attention: paired + XCD-affinity + prefetch ---
// (exact R11 structure: 512 blocks x 256 thr; XCD x = bid&7 hosts heads ≡ x
// (mod 8) -> per-XCD K/V = 4MB = its L2. Wave owns pair (qiL=pi, qiH=63-pi):
// uniform work; K/V fragments loaded ONCE per tile for both blocks; K reg-
// double-buffered. Fixed-shift softmax P = exp2(S-32); no LDS, no barriers.)
__global__ __launch_bounds__(256, 2) void attn_kernel(const ushort_t* __restrict__ Qp,
                                                      const ushort_t* __restrict__ Kp,
                                                      const ushort_t* __restrict__ VT,
                                                      ushort_t* __restrict__ AO) {
    int tid = threadIdx.x;
    int l = tid & 63, w = tid >> 6;
    int lq = l & 31;
    int hi = l >> 5;
    int bid = blockIdx.x;
    int x = bid & 7, jj = bid >> 3;
    int bh = x + 8 * (jj & 7);
    int pi = (jj >> 3) * 4 + w;      // 0..31
    int qiL = pi, qiH = 63 - pi;
    int jlo = (qiL >> 1) + 1;
    int jhi = (qiH >> 1) + 1;
    int b = bh >> 4;

    const size_t hb = (size_t)bh << 17;
    const size_t base = ((size_t)b * NSEQ) * DMODEL + (size_t)(bh & 15) * HDIM;

    int qgL = qiL * 32 + lq;
    int qgH = qiH * 32 + lq;
    int loff = lq * 16 + 8 * hi;

    const ushort_t* kpbase = Kp + hb + loff;
    const ushort_t* vpbase = VT + hb + loff;

    short8 qfL[4], qfH[4];
    {
        const ushort_t* qpL = Qp + hb + ((size_t)qiL << 11) + loff;
        const ushort_t* qpH = Qp + hb + ((size_t)qiH << 11) + loff;
#pragma unroll
        for (int c = 0; c < 4; c++) { qfL[c] = *(const short8*)(qpL + (c << 9));
                                      qfH[c] = *(const short8*)(qpH + (c << 9)); }
    }

    f32x16 OL0 = {}, OL1 = {}, OH0 = {}, OH1 = {};
    float lrunL = 0.f, lrunH = 0.f;

    short8 kA0[4], kA1[4], kB0[4], kB1[4];
#pragma unroll
    for (int c = 0; c < 4; c++) { kA0[c] = *(const short8*)(kpbase + (c << 9));
                                  kA1[c] = *(const short8*)(kpbase + 2048 + (c << 9)); }

    // one tile-step: consume kc*, optionally prefetch next K into kn*
#define ATTN_STEP(kc0, kc1, kn0, kn1, J, PREF) do {                              \
        int j_ = (J); int k0_ = j_ << 6;                                         \
        short8 vf0[4], vf1[4];                                                   \
        { const ushort_t* vp = vpbase + ((size_t)j_ << 12);                      \
          _Pragma("unroll")                                                      \
          for (int c = 0; c < 4; c++) { vf0[c] = *(const short8*)(vp + (c << 9));\
                                        vf1[c] = *(const short8*)(vp + 2048 + (c << 9)); } } \
        /* H: QK -> softmax -> pack */                                           \
        f32x16 S0 = {}, S1 = {};                                                 \
        _Pragma("unroll")                                                        \
        for (int c = 0; c < 4; c++) { S0 = __builtin_amdgcn_mfma_f32_32x32x16_bf16(kc0[c], qfH[c], S0, 0, 0, 0); } \
        _Pragma("unroll")                                                        \
        for (int c = 0; c < 4; c++) { S1 = __builtin_amdgcn_mfma_f32_32x32x16_bf16(kc1[c], qfH[c], S1, 0, 0, 0); } \
        if (j_ == jhi - 1) {                                                     \
            _Pragma("unroll")                                                    \
            for (int r = 0; r < 16; r++) {                                       \
                int kk = k0_ + (r & 3) + 8 * (r >> 2) + 4 * hi;                  \
                if (kk > qgH)      S0[r] = -1e30f;                               \
                if (kk + 32 > qgH) S1[r] = -1e30f;                               \
            }                                                                    \
        }                                                                        \
        float rsH = 0.f;                                                         \
        _Pragma("unroll")                                                        \
        for (int r = 0; r < 16; r++) {                                           \
            S0[r] = __builtin_amdgcn_exp2f(S0[r] - 32.f);                        \
            S1[r] = __builtin_amdgcn_exp2f(S1[r] - 32.f);                        \
            rsH += S0[r] + S1[r];                                                \
        }                                                                        \
        rsH += __shfl_xor(rsH, 32);                                              \
        lrunH += rsH;                                                            \
        short8 pfrH[4];                                                          \
        pack_pfr(S0, S1, pfrH);                                                  \
        /* L: QK (reuses S regs) */                                              \
        bool actL = (j_ < jlo);                                                  \
        if (actL) {                                                              \
            S0 = (f32x16){}; S1 = (f32x16){};                                    \
            _Pragma("unroll")                                                    \
            for (int c = 0; c < 4; c++) { S0 = __builtin_amdgcn_mfma_f32_32x32x16_bf16(kc0[c], qfL[c], S0, 0, 0, 0); } \
            _Pragma("unroll")                                                    \
            for (int c = 0; c < 4; c++) { S1 = __builtin_amdgcn_mfma_f32_32x32x16_bf16(kc1[c], qfL[c], S1, 0, 0, 0); } \
        }                                                                        \
        /* prefetch next K (kc consumed) */                                      \
        if (PREF) {                                                              \
            const ushort_t* kp = kpbase + ((size_t)(2 * (j_ + 1)) << 11);        \
            _Pragma("unroll")                                                    \
            for (int c = 0; c < 4; c++) { kn0[c] = *(const short8*)(kp + (c << 9)); \
                                          kn1[c] = *(const short8*)(kp + 2048 + (c << 9)); } \
        }                                                                        \
        /* PV_H */                                                               \
        _Pragma("unroll")                                                        \
        for (int c = 0; c < 4; c++) { OH0 = __builtin_amdgcn_mfma_f32_32x32x16_bf16(vf0[c], pfrH[c], OH0, 0, 0, 0); } \
        _Pragma("unroll")                                                        \
        for (int c = 0; c < 4; c++) { OH1 = __builtin_amdgcn_mfma_f32_32x32x16_bf16(vf1[c], pfrH[c], OH1, 0, 0, 0); } \
        /* L: softmax -> pack -> PV */                                           \
        if (actL) {                                                              \
            if (j_ == jlo - 1) {                                                 \
                _Pragma("unroll")                                                \
                for (int r = 0; r < 16; r++) {                                   \
                    int kk = k0_ + (r & 3) + 8 * (r >> 2) + 4 * hi;              \
                    if (kk > qgL)      S0[r] = -1e30f;                           \
                    if (kk + 32 > qgL) S1[r] = -1e30f;                           \
                }                                                                \
            }                                                                    \
            float rsL = 0.f;                                                     \
            _Pragma("unroll")                                                    \
            for (int r = 0; r < 16; r++) {                                       \
                S0[r] = __builtin_amdgcn_exp2f(S0[r] - 32.f);                    \
                S1[r] = __builtin_amdgcn_exp2f(S1[r] - 32.f);                    \
                rsL += S0[r] + S1[r];                                            \
            }                                                                    \
            rsL += __shfl_xor(rsL, 32);                                          \
            lrunL += rsL;                                                        \
            short8 pfrL[4];                                                      \
            pack_pfr(S0, S1, pfrL);                                              \
            _Pragma("unroll")                                                    \
            for (int c = 0; c < 4; c++) { OL0 = __builtin_amdgcn_mfma_f32_32x32x16_bf16(vf0[c], pfrL[c], OL0, 0, 0, 0); } \
            _Pragma("unroll")                                                    \
            for (int c = 0; c < 4; c++) { OL1 = __builtin_amdgcn_mfma_f32_32x32x16_bf16(vf1[c], pfrL[c], OL1, 0, 0, 0); } \
        }                                                                        \
    } while (0)

    int j = 0;
    for (; j + 1 < jhi; j += 2) {
        ATTN_STEP(kA0, kA1, kB0, kB1, j, true);
        ATTN_STEP(kB0, kB1, kA0, kA1, j + 1, (j + 2 < jhi));
    }
    if (j < jhi) ATTN_STEP(kA0, kA1, kB0, kB1, j, false);
#undef ATTN_STEP

    // ---- epilogue: both q-blocks ----
    {
        float inv = 1.f / lrunL;
        size_t rowoff = base + (size_t)qgL * DMODEL;
#pragma unroll
        for (int q4 = 0; q4 < 4; q4++) {
            uint2 ua = {cvt_pk_bf16(OL0[4 * q4] * inv,     OL0[4 * q4 + 1] * inv),
                        cvt_pk_bf16(OL0[4 * q4 + 2] * inv, OL0[4 * q4 + 3] * inv)};
            *(uint2*)(AO + rowoff + 8 * q4 + 4 * hi) = ua;
            uint2 ub = {cvt_pk_bf16(OL1[4 * q4] * inv,     OL1[4 * q4 + 1] * inv),
                        cvt_pk_bf16(OL1[4 * q4 + 2] * inv, OL1[4 * q4 + 3] * inv)};
            *(uint2*)(AO + rowoff + 32 + 8 * q4 + 4 * hi) = ub;
        }
    }
    {
        float inv = 1.f / lrunH;
        size_t rowoff = base + (size_t)qgH * DMODEL;
#pragma unroll
        for (int q4 = 0; q4 < 4; q4++) {
            uint2 ua = {cvt_pk_bf16(OH0[4 * q4] * inv,     OH0[4 * q4 + 1] * inv),
                        cvt_pk_bf16(OH0[4 * q4 + 2] * inv, OH0[4 * q4 + 3] * inv)};
            *(uint2*)(AO + rowoff + 8 * q4 + 4 * hi) = ua;
            uint2 ub = {cvt_pk_bf16(OH1[4 * q4] * inv,     OH1[4 * q4 + 1] * inv),
                        cvt_pk_bf16(OH1[4 * q4 + 2] * inv, OH1[4 * q4 + 3] * inv)};
            *(uint2*)(AO + rowoff + 32 + 8 * q4 + 4 * hi) = ub;
        }
    }
}

// ---------------- launch ----------------
extern "C" void kernel_launch(void* const* d_in, const int* in_sizes, int n_in,
                              void* d_out, int out_size, void* d_ws, size_t ws_size,
                              hipStream_t stream) {
    const float* q  = (const float*)d_in[0];
    const float* k  = (const float*)d_in[1];
    const float* v  = (const float*)d_in[2];
    const float* Wq = (const float*)d_in[3];
    const float* Wk = (const float*)d_in[4];
    const float* Wv = (const float*)d_in[5];
    const float* Wo = (const float*)d_in[6];
    float* out = (float*)d_out;

    const size_t BND = (size_t)BATCH * NSEQ * DMODEL;   // 8388608
    const size_t WSZ = (size_t)DMODEL * DMODEL;         // 1048576
    const size_t need = (7 * BND + 4 * WSZ) * sizeof(ushort_t);  // ~120 MB
    if (ws_size < need) return;

    ushort_t* ws  = (ushort_t*)d_ws;
    ushort_t* qb  = ws;
    ushort_t* kb  = qb + BND;
    ushort_t* vb  = kb + BND;
    ushort_t* Qp  = vb + BND;   // fragment-tiled
    ushort_t* Kp  = Qp + BND;   // fragment-tiled
    ushort_t* VT  = Kp + BND;   // fragment-tiled (transposed)
    ushort_t* AO  = VT + BND;   // row-major
    ushort_t* Wqb = AO + BND;   // 4 weights contiguous

    const int M = BATCH * NSEQ;  // 8192

    cvt_all<<<2048, 256, 0, stream>>>(q, k, v, Wq, Wk, Wv, Wo, qb, Wqb);

    int gblocks = (M / 256) * (DMODEL / 128);  // 256 blocks
    // scores scale 1/sqrt(64) * log2(e) folded into Q projection (exp2-domain softmax)
    gemm_bt8<ushort_t, 1><<<gblocks, 512, 0, stream>>>(qb, Wqb, Qp, M, DMODEL, DMODEL, 0.18033688011112043f);
    gemm_bt8<ushort_t, 1><<<gblocks, 512, 0, stream>>>(kb, Wqb + WSZ, Kp, M, DMODEL, DMODEL, 1.0f);
    gemm_bt8<ushort_t, 2><<<gblocks, 512, 0, stream>>>(vb, Wqb + 2 * WSZ, VT, M, DMODEL, DMODEL, 1.0f);

    attn_kernel<<<512, 256, 0, stream>>>(Qp, Kp, VT, AO);

    gemm_bt8<float, 0><<<gblocks, 512, 0, stream>>>(AO, Wqb + 3 * WSZ, out, M, DMODEL, DMODEL, 1.0f);
}

// Round 24
// 166.840 us; speedup vs baseline: 1.0085x; 1.0061x over previous
//
#include <hip/hip_runtime.h>
#include <hip/hip_bf16.h>

// B=4, N=2048, D=1024, H=16, HD=64
#define BATCH 4
#define NSEQ 2048
#define DMODEL 1024
#define NHEAD 16
#define HDIM 64

typedef __attribute__((ext_vector_type(8))) short short8;
typedef __attribute__((ext_vector_type(4))) float f32x4;
typedef __attribute__((ext_vector_type(16))) float f32x16;
typedef __attribute__((ext_vector_type(2))) int int2v;
typedef unsigned short ushort_t;

__device__ __forceinline__ ushort_t f2bf(float f) {
    union { float f; unsigned u; } x; x.f = f;
    unsigned r = x.u + 0x7fffu + ((x.u >> 16) & 1u);   // round-to-nearest-even
    return (ushort_t)(r >> 16);
}

__device__ __forceinline__ unsigned cvt_pk_bf16(float lo, float hi) {
    unsigned r;
    asm("v_cvt_pk_bf16_f32 %0, %1, %2" : "=v"(r) : "v"(lo), "v"(hi));
    return r;
}

// async global->LDS, 16B per lane, dest = wave-uniform base + lane*16
#define GLOAD16(gp, lp) __builtin_amdgcn_global_load_lds(                       \
    (const __attribute__((address_space(1))) unsigned*)(const void*)(gp),       \
    (__attribute__((address_space(3))) unsigned*)(void*)(lp), 16, 0, 0)

// ---------------- fused fp32 -> bf16 convert (single launch, grid-stride) ----
// chunks: 0..12287 = q/k/v (4096 each -> qkv buffer); 12288..14335 = weights.
__global__ __launch_bounds__(256) void cvt_all(const float* __restrict__ q,
                                               const float* __restrict__ k,
                                               const float* __restrict__ v,
                                               const float* __restrict__ w0,
                                               const float* __restrict__ w1,
                                               const float* __restrict__ w2,
                                               const float* __restrict__ w3,
                                               ushort_t* __restrict__ oqkv,
                                               ushort_t* __restrict__ ow) {
    for (int chunk = blockIdx.x; chunk < 14336; chunk += (int)gridDim.x) {
        const float* in;
        ushort_t* out;
        size_t i;
        if (chunk < 12288) {
            int which = chunk >> 12, lb = chunk & 4095;
            in = (which == 0) ? q : ((which == 1) ? k : v);
            i = ((size_t)lb * 256 + threadIdx.x) * 8;
            out = oqkv + (size_t)which * 8388608;
        } else {
            int wb = chunk - 12288;
            int which = wb >> 9, lb = wb & 511;
            in = (which == 0) ? w0 : ((which == 1) ? w1 : ((which == 2) ? w2 : w3));
            i = ((size_t)lb * 256 + threadIdx.x) * 8;
            out = ow + (size_t)which * 1048576;
        }
        float4 f0 = *(const float4*)(in + i);
        float4 f1 = *(const float4*)(in + i + 4);
        short8 o;
        o[0] = f2bf(f0.x); o[1] = f2bf(f0.y); o[2] = f2bf(f0.z); o[3] = f2bf(f0.w);
        o[4] = f2bf(f1.x); o[5] = f2bf(f1.y); o[6] = f2bf(f1.z); o[7] = f2bf(f1.w);
        *(short8*)(out + i) = o;
    }
}

// ---------------- deep-pipelined bf16 GEMM (R7/R11 proven version) -----------
// BM=256 BN=128 BK=64, 512 threads (8 waves, 4Mx2N), 3-slot LDS rotation,
// counted vmcnt(6), T2 XOR-swizzle both sides, T5 setprio.
__device__ __forceinline__ void storeC(float* C, size_t idx, float v) { C[idx] = v; }
__device__ __forceinline__ void storeC(ushort_t* C, size_t idx, float v) { C[idx] = f2bf(v); }

template <typename OutT, int LAYOUT>
__global__ __launch_bounds__(512) void gemm_bt8(const ushort_t* __restrict__ A,
                                                const ushort_t* __restrict__ Bt,
                                                OutT* __restrict__ C,
                                                int M, int N, int K, float alpha) {
    __shared__ ushort_t As[3][256 * 64];
    __shared__ ushort_t Bs[3][128 * 64];

    int tid = threadIdx.x;
    int l = tid & 63, w = tid >> 6;
    int wm = w >> 1, wn = w & 1;
    int lr = l & 15, lk = l >> 4;

    int bid = blockIdx.x;
    int wg = (bid & 7) * 32 + (bid >> 3);
    int nbc = N >> 7;
    int brow = (wg / nbc) << 8;
    int bcol = (wg % nbc) << 7;

    int srow8 = l >> 3;
    int sx = ((l & 7) ^ srow8) * 8;
    const ushort_t* pAsrc = A + (size_t)(brow + w * 32 + srow8) * K + sx;
    const ushort_t* pBsrc = Bt + (size_t)(bcol + w * 16 + srow8) * K + sx;
    const size_t rowK8 = (size_t)8 * K;

    int colx = (lk << 4) ^ ((lr & 7) << 4);
    int abyte = (wm * 64 + lr) * 128 + colx;
    int bbyte = (wn * 64 + lr) * 128 + colx;

    f32x4 acc[4][4] = {};
    const int NT = K >> 6;

#pragma unroll
    for (int c = 0; c < 4; c++) GLOAD16(pAsrc + c * rowK8,      &As[0][(w * 32 + 8 * c) * 64]);
#pragma unroll
    for (int c = 0; c < 2; c++) GLOAD16(pBsrc + c * rowK8,      &Bs[0][(w * 16 + 8 * c) * 64]);
#pragma unroll
    for (int c = 0; c < 4; c++) GLOAD16(pAsrc + c * rowK8 + 64, &As[1][(w * 32 + 8 * c) * 64]);
#pragma unroll
    for (int c = 0; c < 2; c++) GLOAD16(pBsrc + c * rowK8 + 64, &Bs[1][(w * 16 + 8 * c) * 64]);

    int slot = 0, stslot = 2;
    for (int T = 0; T < NT; ++T) {
        if (T < NT - 1) { asm volatile("s_waitcnt vmcnt(6)" ::: "memory"); }
        else            { asm volatile("s_waitcnt vmcnt(0)" ::: "memory"); }
        __builtin_amdgcn_sched_barrier(0);
        __builtin_amdgcn_s_barrier();
        asm volatile("" ::: "memory");

        const char* ab = (const char*)&As[slot][0];
        const char* bb = (const char*)&Bs[slot][0];
        bool stage = (T + 2 < NT);
        int k2 = (T + 2) << 6;

        short8 af[4], bf_[4];
#pragma unroll
        for (int m = 0; m < 4; m++) af[m]  = *(const short8*)(ab + abyte + m * 2048);
#pragma unroll
        for (int n = 0; n < 4; n++) bf_[n] = *(const short8*)(bb + bbyte + n * 2048);
        if (stage) {
            GLOAD16(pAsrc + 0 * rowK8 + k2, &As[stslot][(w * 32 + 0) * 64]);
            GLOAD16(pAsrc + 1 * rowK8 + k2, &As[stslot][(w * 32 + 8) * 64]);
            GLOAD16(pAsrc + 2 * rowK8 + k2, &As[stslot][(w * 32 + 16) * 64]);
        }
        __builtin_amdgcn_s_setprio(1);
#pragma unroll
        for (int m = 0; m < 4; m++)
#pragma unroll
            for (int n = 0; n < 4; n++)
                acc[m][n] = __builtin_amdgcn_mfma_f32_16x16x32_bf16(af[m], bf_[n], acc[m][n], 0, 0, 0);
        __builtin_amdgcn_s_setprio(0);

#pragma unroll
        for (int m = 0; m < 4; m++) af[m]  = *(const short8*)(ab + (abyte ^ 64) + m * 2048);
#pragma unroll
        for (int n = 0; n < 4; n++) bf_[n] = *(const short8*)(bb + (bbyte ^ 64) + n * 2048);
        if (stage) {
            GLOAD16(pAsrc + 3 * rowK8 + k2, &As[stslot][(w * 32 + 24) * 64]);
            GLOAD16(pBsrc + 0 * rowK8 + k2, &Bs[stslot][(w * 16 + 0) * 64]);
            GLOAD16(pBsrc + 1 * rowK8 + k2, &Bs[stslot][(w * 16 + 8) * 64]);
        }
        __builtin_amdgcn_s_setprio(1);
#pragma unroll
        for (int m = 0; m < 4; m++)
#pragma unroll
            for (int n = 0; n < 4; n++)
                acc[m][n] = __builtin_amdgcn_mfma_f32_16x16x32_bf16(af[m], bf_[n], acc[m][n], 0, 0, 0);
        __builtin_amdgcn_s_setprio(0);

        slot = (slot == 2) ? 0 : slot + 1;
        stslot = (stslot == 2) ? 0 : stslot + 1;
    }

#pragma unroll
    for (int m = 0; m < 4; m++)
#pragma unroll
        for (int n = 0; n < 4; n++)
#pragma unroll
            for (int r = 0; r < 4; r++) {
                int row = brow + wm * 64 + m * 16 + lk * 4 + r;
                int col = bcol + wn * 64 + n * 16 + lr;
                float v = acc[m][n][r] * alpha;
                if (LAYOUT == 0) {
                    storeC(C, (size_t)row * N + col, v);
                } else if (LAYOUT == 1) {
                    int b = row >> 11, nn = row & 2047, h = col >> 6, d = col & 63;
                    size_t idx = ((size_t)(b * NHEAD + h) << 17) + ((size_t)(nn >> 5) << 11) +
                                 ((d >> 4) << 9) + ((nn & 31) << 4) + (d & 15);
                    storeC(C, idx, v);
                } else {
                    int b = row >> 11, kk = row & 2047, h = col >> 6, d = col & 63;
                    size_t idx = ((size_t)(b * NHEAD + h) << 17) + ((size_t)(kk >> 6) << 12) +
                                 ((d >> 5) << 11) + (((kk >> 4) & 3) << 9) + ((d & 31) << 4) + (kk & 15);
                    storeC(C, idx, v);
                }
            }
}

// -------- T12 pack: S (f32x16 pair) -> bf16 B-operand fragments --------------
__device__ __forceinline__ void pack_pfr(const f32x16& S0, const f32x16& S1, short8 (&pfr)[4]) {
    unsigned pw0[8], pw1[8];
#pragma unroll
    for (int jj = 0; jj < 8; jj++) {
        pw0[jj] = cvt_pk_bf16(S0[2 * jj], S0[2 * jj + 1]);
        pw1[jj] = cvt_pk_bf16(S1[2 * jj], S1[2 * jj + 1]);
    }
    union U { unsigned u[4]; short8 s; };
    int2v a, bb;
    a  = __builtin_amdgcn_permlane32_swap((int)pw0[0], (int)pw0[2], false, false);
    bb = __builtin_amdgcn_permlane32_swap((int)pw0[1], (int)pw0[3], false, false);
    U u0; u0.u[0] = (unsigned)a[0]; u0.u[1] = (unsigned)bb[0];
          u0.u[2] = (unsigned)a[1]; u0.u[3] = (unsigned)bb[1];
    pfr[0] = u0.s;
    a  = __builtin_amdgcn_permlane32_swap((int)pw0[4], (int)pw0[6], false, false);
    bb = __builtin_amdgcn_permlane32_swap((int)pw0[5], (int)pw0[7], false, false);
    U u1; u1.u[0] = (unsigned)a[0]; u1.u[1] = (unsigned)bb[0];
          u1.u[2] = (unsigned)a[1]; u1.u[3] = (unsigned)bb[1];
    pfr[1] = u1.s;
    a  = __builtin_amdgcn_permlane32_swap((int)pw1[0], (int)pw1[2], false, false);
    bb = __builtin_amdgcn_permlane32_swap((int)pw1[1], (int)pw1[3], false, false);
    U u2; u2.u[0] = (unsigned)a[0]; u2.u[1] = (unsigned)bb[0];
          u2.u[2] = (unsigned)a[1]; u2.u[3] = (unsigned)bb[1];
    pfr[2] = u2.s;
    a  = __builtin_amdgcn_permlane32_swap((int)pw1[4], (int)pw1[6], false, false);
    bb = __builtin_amdgcn_permlane32_swap((int)pw1[5], (int)pw1[7], false, false);
    U u3; u3.u[0] = (unsigned)a[0]; u3.u[1] = (unsigned)bb[0];
          u3.u[2] = (unsigned)a[1]; u3.u[3] = (unsigned)bb[1];
    pfr[3] = u3.s;
}

// ---------------- causal flash attention: paired + XCD-affinity + prefetch ---
// (exact R11 structure: 512 blocks x 256 thr; XCD x = bid&7 hosts heads ≡ x
// (mod 8) -> per-XCD K/V = 4MB = its L2. Wave owns pair (qiL=pi, qiH=63-pi):
// uniform work; K/V fragments loaded ONCE per tile for both blocks; K reg-
// double-buffered. Fixed-shift softmax P = exp2(S-32); no LDS, no barriers.)
__global__ __launch_bounds__(256, 2) void attn_kernel(const ushort_t* __restrict__ Qp,
                                                      const ushort_t* __restrict__ Kp,
                                                      const ushort_t* __restrict__ VT,
                                                      ushort_t* __restrict__ AO) {
    int tid = threadIdx.x;
    int l = tid & 63, w = tid >> 6;
    int lq = l & 31;
    int hi = l >> 5;
    int bid = blockIdx.x;
    int x = bid & 7, jj = bid >> 3;
    int bh = x + 8 * (jj & 7);
    int pi = (jj >> 3) * 4 + w;      // 0..31
    int qiL = pi, qiH = 63 - pi;
    int jlo = (qiL >> 1) + 1;
    int jhi = (qiH >> 1) + 1;
    int b = bh >> 4;

    const size_t hb = (size_t)bh << 17;
    const size_t base = ((size_t)b * NSEQ) * DMODEL + (size_t)(bh & 15) * HDIM;

    int qgL = qiL * 32 + lq;
    int qgH = qiH * 32 + lq;
    int loff = lq * 16 + 8 * hi;

    const ushort_t* kpbase = Kp + hb + loff;
    const ushort_t* vpbase = VT + hb + loff;

    short8 qfL[4], qfH[4];
    {
        const ushort_t* qpL = Qp + hb + ((size_t)qiL << 11) + loff;
        const ushort_t* qpH = Qp + hb + ((size_t)qiH << 11) + loff;
#pragma unroll
        for (int c = 0; c < 4; c++) { qfL[c] = *(const short8*)(qpL + (c << 9));
                                      qfH[c] = *(const short8*)(qpH + (c << 9)); }
    }

    f32x16 OL0 = {}, OL1 = {}, OH0 = {}, OH1 = {};
    float lrunL = 0.f, lrunH = 0.f;

    short8 kA0[4], kA1[4], kB0[4], kB1[4];
#pragma unroll
    for (int c = 0; c < 4; c++) { kA0[c] = *(const short8*)(kpbase + (c << 9));
                                  kA1[c] = *(const short8*)(kpbase + 2048 + (c << 9)); }

    // one tile-step: consume kc*, optionally prefetch next K into kn*
#define ATTN_STEP(kc0, kc1, kn0, kn1, J, PREF) do {                              \
        int j_ = (J); int k0_ = j_ << 6;                                         \
        short8 vf0[4], vf1[4];                                                   \
        { const ushort_t* vp = vpbase + ((size_t)j_ << 12);                      \
          _Pragma("unroll")                                                      \
          for (int c = 0; c < 4; c++) { vf0[c] = *(const short8*)(vp + (c << 9));\
                                        vf1[c] = *(const short8*)(vp + 2048 + (c << 9)); } } \
        /* H: QK -> softmax -> pack */                                           \
        f32x16 S0 = {}, S1 = {};                                                 \
        _Pragma("unroll")                                                        \
        for (int c = 0; c < 4; c++) { S0 = __builtin_amdgcn_mfma_f32_32x32x16_bf16(kc0[c], qfH[c], S0, 0, 0, 0); } \
        _Pragma("unroll")                                                        \
        for (int c = 0; c < 4; c++) { S1 = __builtin_amdgcn_mfma_f32_32x32x16_bf16(kc1[c], qfH[c], S1, 0, 0, 0); } \
        if (j_ == jhi - 1) {                                                     \
            _Pragma("unroll")                                                    \
            for (int r = 0; r < 16; r++) {                                       \
                int kk = k0_ + (r & 3) + 8 * (r >> 2) + 4 * hi;                  \
                if (kk > qgH)      S0[r] = -1e30f;                               \
                if (kk + 32 > qgH) S1[r] = -1e30f;                               \
            }                                                                    \
        }                                                                        \
        float rsH = 0.f;                                                         \
        _Pragma("unroll")                                                        \
        for (int r = 0; r < 16; r++) {                                           \
            S0[r] = __builtin_amdgcn_exp2f(S0[r] - 32.f);                        \
            S1[r] = __builtin_amdgcn_exp2f(S1[r] - 32.f);                        \
            rsH += S0[r] + S1[r];                                                \
        }                                                                        \
        rsH += __shfl_xor(rsH, 32);                                              \
        lrunH += rsH;                                                            \
        short8 pfrH[4];                                                          \
        pack_pfr(S0, S1, pfrH);                                                  \
        /* L: QK (reuses S regs) */                                              \
        bool actL = (j_ < jlo);                                                  \
        if (actL) {                                                              \
            S0 = (f32x16){}; S1 = (f32x16){};                                    \
            _Pragma("unroll")                                                    \
            for (int c = 0; c < 4; c++) { S0 = __builtin_amdgcn_mfma_f32_32x32x16_bf16(kc0[c], qfL[c], S0, 0, 0, 0); } \
            _Pragma("unroll")                                                    \
            for (int c = 0; c < 4; c++) { S1 = __builtin_amdgcn_mfma_f32_32x32x16_bf16(kc1[c], qfL[c], S1, 0, 0, 0); } \
        }                                                                        \
        /* prefetch next K (kc consumed) */                                      \
        if (PREF) {                                                              \
            const ushort_t* kp = kpbase + ((size_t)(2 * (j_ + 1)) << 11);        \
            _Pragma("unroll")                                                    \
            for (int c = 0; c < 4; c++) { kn0[c] = *(const short8*)(kp + (c << 9)); \
                                          kn1[c] = *(const short8*)(kp + 2048 + (c << 9)); } \
        }                                                                        \
        /* PV_H */                                                               \
        _Pragma("unroll")                                                        \
        for (int c = 0; c < 4; c++) { OH0 = __builtin_amdgcn_mfma_f32_32x32x16_bf16(vf0[c], pfrH[c], OH0, 0, 0, 0); } \
        _Pragma("unroll")                                                        \
        for (int c = 0; c < 4; c++) { OH1 = __builtin_amdgcn_mfma_f32_32x32x16_bf16(vf1[c], pfrH[c], OH1, 0, 0, 0); } \
        /* L: softmax -> pack -> PV */                                           \
        if (actL) {                                                              \
            if (j_ == jlo - 1) {                                                 \
                _Pragma("unroll")                                                \
                for (int r = 0; r < 16; r++) {                                   \
                    int kk = k0_ + (r & 3) + 8 * (r >> 2) + 4 * hi;              \
                    if (kk > qgL)      S0[r] = -1e30f;                           \
                    if (kk + 32 > qgL) S1[r] = -1e30f;                           \
                }                                                                \
            }                                                                    \
            float rsL = 0.f;                                                     \
            _Pragma("unroll")                                                    \
            for (int r = 0; r < 16; r++) {                                       \
                S0[r] = __builtin_amdgcn_exp2f(S0[r] - 32.f);                    \
                S1[r] = __builtin_amdgcn_exp2f(S1[r] - 32.f);                    \
                rsL += S0[r] + S1[r];                                            \
            }                                                                    \
            rsL += __shfl_xor(rsL, 32);                                          \
            lrunL += rsL;                                                        \
            short8 pfrL[4];                                                      \
            pack_pfr(S0, S1, pfrL);                                              \
            _Pragma("unroll")                                                    \
            for (int c = 0; c < 4; c++) { OL0 = __builtin_amdgcn_mfma_f32_32x32x16_bf16(vf0[c], pfrL[c], OL0, 0, 0, 0); } \
            _Pragma("unroll")                                                    \
            for (int c = 0; c < 4; c++) { OL1 = __builtin_amdgcn_mfma_f32_32x32x16_bf16(vf1[c], pfrL[c], OL1, 0, 0, 0); } \
        }                                                                        \
    } while (0)

    int j = 0;
    for (; j + 1 < jhi; j += 2) {
        ATTN_STEP(kA0, kA1, kB0, kB1, j, true);
        ATTN_STEP(kB0, kB1, kA0, kA1, j + 1, (j + 2 < jhi));
    }
    if (j < jhi) ATTN_STEP(kA0, kA1, kB0, kB1, j, false);
#undef ATTN_STEP

    // ---- epilogue: both q-blocks ----
    {
        float inv = 1.f / lrunL;
        size_t rowoff = base + (size_t)qgL * DMODEL;
#pragma unroll
        for (int q4 = 0; q4 < 4; q4++) {
            uint2 ua = {cvt_pk_bf16(OL0[4 * q4] * inv,     OL0[4 * q4 + 1] * inv),
                        cvt_pk_bf16(OL0[4 * q4 + 2] * inv, OL0[4 * q4 + 3] * inv)};
            *(uint2*)(AO + rowoff + 8 * q4 + 4 * hi) = ua;
            uint2 ub = {cvt_pk_bf16(OL1[4 * q4] * inv,     OL1[4 * q4 + 1] * inv),
                        cvt_pk_bf16(OL1[4 * q4 + 2] * inv, OL1[4 * q4 + 3] * inv)};
            *(uint2*)(AO + rowoff + 32 + 8 * q4 + 4 * hi) = ub;
        }
    }
    {
        float inv = 1.f / lrunH;
        size_t rowoff = base + (size_t)qgH * DMODEL;
#pragma unroll
        for (int q4 = 0; q4 < 4; q4++) {
            uint2 ua = {cvt_pk_bf16(OH0[4 * q4] * inv,     OH0[4 * q4 + 1] * inv),
                        cvt_pk_bf16(OH0[4 * q4 + 2] * inv, OH0[4 * q4 + 3] * inv)};
            *(uint2*)(AO + rowoff + 8 * q4 + 4 * hi) = ua;
            uint2 ub = {cvt_pk_bf16(OH1[4 * q4] * inv,     OH1[4 * q4 + 1] * inv),
                        cvt_pk_bf16(OH1[4 * q4 + 2] * inv, OH1[4 * q4 + 3] * inv)};
            *(uint2*)(AO + rowoff + 32 + 8 * q4 + 4 * hi) = ub;
        }
    }
}

// ---------------- launch ----------------
extern "C" void kernel_launch(void* const* d_in, const int* in_sizes, int n_in,
                              void* d_out, int out_size, void* d_ws, size_t ws_size,
                              hipStream_t stream) {
    const float* q  = (const float*)d_in[0];
    const float* k  = (const float*)d_in[1];
    const float* v  = (const float*)d_in[2];
    const float* Wq = (const float*)d_in[3];
    const float* Wk = (const float*)d_in[4];
    const float* Wv = (const float*)d_in[5];
    const float* Wo = (const float*)d_in[6];
    float* out = (float*)d_out;

    const size_t BND = (size_t)BATCH * NSEQ * DMODEL;   // 8388608
    const size_t WSZ = (size_t)DMODEL * DMODEL;         // 1048576
    const size_t need = (7 * BND + 4 * WSZ) * sizeof(ushort_t);  // ~120 MB
    if (ws_size < need) return;

    ushort_t* ws  = (ushort_t*)d_ws;
    ushort_t* qb  = ws;
    ushort_t* kb  = qb + BND;
    ushort_t* vb  = kb + BND;
    ushort_t* Qp  = vb + BND;   // fragment-tiled
    ushort_t* Kp  = Qp + BND;   // fragment-tiled
    ushort_t* VT  = Kp + BND;   // fragment-tiled (transposed)
    ushort_t* AO  = VT + BND;   // row-major
    ushort_t* Wqb = AO + BND;   // 4 weights contiguous

    const int M = BATCH * NSEQ;  // 8192

    cvt_all<<<2048, 256, 0, stream>>>(q, k, v, Wq, Wk, Wv, Wo, qb, Wqb);

    int gblocks = (M / 256) * (DMODEL / 128);  // 256 blocks
    // scores scale 1/sqrt(64) * log2(e) folded into Q projection (exp2-domain softmax)
    gemm_bt8<ushort_t, 1><<<gblocks, 512, 0, stream>>>(qb, Wqb, Qp, M, DMODEL, DMODEL, 0.18033688011112043f);
    gemm_bt8<ushort_t, 1><<<gblocks, 512, 0, stream>>>(kb, Wqb + WSZ, Kp, M, DMODEL, DMODEL, 1.0f);
    gemm_bt8<ushort_t, 2><<<gblocks, 512, 0, stream>>>(vb, Wqb + 2 * WSZ, VT, M, DMODEL, DMODEL, 1.0f);

    attn_kernel<<<512, 256, 0, stream>>>(Qp, Kp, VT, AO);

    gemm_bt8<float, 0><<<gblocks, 512, 0, stream>>>(AO, Wqb + 3 * WSZ, out, M, DMODEL, DMODEL, 1.0f);
}